// Round 19
// baseline (81.201 us; speedup 1.0000x reference)
//
#include <hip/hip_runtime.h>
#include <math.h>

#define BB 64
#define LL 256
#define DD 1024
#define NDPAD 512   // padded anti-diagonal count per batch (511 real + 1 pad)
#define BK 32
#define LOG2E 1.4426950408889634f
#define LN2   0.6931471805599453f

typedef __attribute__((ext_vector_type(8))) short short8v;
typedef __attribute__((ext_vector_type(4))) float float4v;

__device__ __forceinline__ unsigned short f2bf(float f) {
    unsigned u = __float_as_uint(f);
    unsigned r = (u + 0x7fffu + ((u >> 16) & 1u)) >> 16;   // RNE
    return (unsigned short)r;
}
__device__ __forceinline__ float bf2f(unsigned short u) {
    return __uint_as_float(((unsigned)u) << 16);
}
// packed RNE convert: dst = (bf16(hi)<<16) | bf16(lo)
__device__ __forceinline__ unsigned cvtpk(float lo, float hi) {
    unsigned r;
    asm("v_cvt_pk_bf16_f32 %0, %1, %2" : "=v"(r) : "v"(lo), "v"(hi));
    return r;
}

// ---------- fused: fp32 load -> bf16 LDS staging + row norms + MFMA dist GEMM ----------
// 64x64 tile, grid (BB, 16) = 1024 blocks x 256 thr (4 waves) => ~4 blocks/CU
// co-resident. R11-R18 showed every schedule at 1 block/CU pins at ~58us (all
// stalls exposed); multi-block TLP lets sibling blocks fill barrier/vmcnt drains
// (m114/m97 mechanism). Tiles of batch b all map to XCD b%8 (ids b+64t) -> the
// 4x S/T row re-reads dedup in that XCD's L2.
// LDS: [row][32 bf16], 16B slot s of row r at phys slot s^((r>>1)&3) (R16 layout,
// measured 0 bank conflicts on both ds_write_b128 and ds_read_b128).
__global__ __launch_bounds__(256) void fused_kernel(const float* __restrict__ S,
                                                    const float* __restrict__ T,
                                                    unsigned short* __restrict__ Dd) {
    __shared__ unsigned short lds[2][2][64 * BK];   // [buf][A/B], 16 KB
    __shared__ float nrm[2][64];                    // row norms [side][local row]

    const int b    = blockIdx.x;
    const int tile = blockIdx.y;                    // 0..15
    const int i0 = (tile & 3) * 64;
    const int j0 = (tile >> 2) * 64;
    const int tid = threadIdx.x, w = tid >> 6, lane = tid & 63;
    const int wr = w >> 1, wc = w & 1;              // wave output tile (32x32)

    const float* Sg = S + ((size_t)b * LL + i0) * DD;
    const float* Tg = T + ((size_t)b * LL + j0) * DD;

    const int sr   = tid >> 2;               // staging row 0..63 (A and B)
    const int slot = tid & 3;                // lds PHYS 32B k-slot this thread fills
    const int kb   = slot ^ ((sr >> 1) & 3); // GLOBAL k-slot (conflict-free swizzle)

    float4v acc[2][2];
    const float4v fzero = {0.f, 0.f, 0.f, 0.f};
    #pragma unroll
    for (int mi = 0; mi < 2; ++mi)
        #pragma unroll
        for (int ni = 0; ni < 2; ++ni) acc[mi][ni] = fzero;

    struct Stg { float4 a0, a1, b0, b1; };   // 8 floats A + 8 floats B
    Stg st0, st1;
    float nsA = 0.0f, nsB = 0.0f;

    auto issue = [&](Stg& s, int kt) {
        const float* pa = Sg + (size_t)sr * DD + kt * BK + kb * 8;
        const float* pb = Tg + (size_t)sr * DD + kt * BK + kb * 8;
        s.a0 = *(const float4*)(pa);
        s.a1 = *(const float4*)(pa + 4);
        s.b0 = *(const float4*)(pb);
        s.b1 = *(const float4*)(pb + 4);
    };

    auto cvtwrite = [&](const float4& v0, const float4& v1, unsigned short* dst, float& nacc) {
        nacc += v0.x * v0.x + v0.y * v0.y + v0.z * v0.z + v0.w * v0.w
              + v1.x * v1.x + v1.y * v1.y + v1.z * v1.z + v1.w * v1.w;
        uint4 o;
        o.x = cvtpk(v0.x, v0.y);
        o.y = cvtpk(v0.z, v0.w);
        o.z = cvtpk(v1.x, v1.y);
        o.w = cvtpk(v1.z, v1.w);
        *(uint4*)dst = o;
    };

    auto commit = [&](Stg& s, int buf) {
        cvtwrite(s.a0, s.a1, &lds[buf][0][sr * BK + slot * 8], nsA);
        cvtwrite(s.b0, s.b1, &lds[buf][1][sr * BK + slot * 8], nsB);
    };

    auto compute = [&](int buf) {
        const unsigned short* LA = &lds[buf][0][0];
        const unsigned short* LB = &lds[buf][1][0];
        short8v af[2], bf[2];
        #pragma unroll
        for (int mi = 0; mi < 2; ++mi) {
            int row = wr * 32 + mi * 16 + (lane & 15);
            int kbf = (lane >> 4) ^ ((row >> 1) & 3);   // conflict-free read swizzle
            af[mi] = *(const short8v*)(LA + row * BK + kbf * 8);
        }
        #pragma unroll
        for (int ni = 0; ni < 2; ++ni) {
            int row = wc * 32 + ni * 16 + (lane & 15);
            int kbf = (lane >> 4) ^ ((row >> 1) & 3);
            bf[ni] = *(const short8v*)(LB + row * BK + kbf * 8);
        }
        #pragma unroll
        for (int mi = 0; mi < 2; ++mi)
            #pragma unroll
            for (int ni = 0; ni < 2; ++ni)
                acc[mi][ni] = __builtin_amdgcn_mfma_f32_16x16x32_bf16(af[mi], bf[ni],
                                                                      acc[mi][ni], 0, 0, 0);
    };

    issue(st0, 0);
    for (int kt2 = 0; kt2 < 32; kt2 += 2) {
        issue(st1, kt2 + 1);
        commit(st0, 0);
        __syncthreads();
        compute(0);
        if (kt2 + 2 < 32) issue(st0, kt2 + 2);
        commit(st1, 1);
        __syncthreads();
        compute(1);
    }

    // row norms: reduce across the 4 slot-lanes of each row
    {
        float s = nsA;
        s += __shfl_xor(s, 1, 64);
        s += __shfl_xor(s, 2, 64);
        if (slot == 0) nrm[0][sr] = s;
        float t = nsB;
        t += __shfl_xor(t, 1, 64);
        t += __shfl_xor(t, 2, 64);
        if (slot == 0) nrm[1][sr] = t;
    }
    __syncthreads();

    // epilogue: sq = ||s||^2 + ||t||^2 - 2*dot -> sqrt -> bf16 * LOG2E, diag-major
    const int r0 = (lane >> 4) * 4;
    const int cf = lane & 15;
    unsigned short* Db = Dd + (size_t)b * NDPAD * 256;
    #pragma unroll
    for (int mi = 0; mi < 2; ++mi) {
        #pragma unroll
        for (int ni = 0; ni < 2; ++ni) {
            int lj = wc * 32 + ni * 16 + cf;
            float tj = nrm[1][lj];
            int j = j0 + lj;
            #pragma unroll
            for (int rg = 0; rg < 4; ++rg) {
                int li = wr * 32 + mi * 16 + r0 + rg;
                float sq = nrm[0][li] + tj - 2.0f * acc[mi][ni][rg];
                float dv = sqrtf(fmaxf(sq, 1e-12f));
                int i = i0 + li;
                Db[(size_t)(i + j) * 256 + j] = f2bf(dv * LOG2E);
            }
        }
    }
}

// ---------- soft-DTW DP: 4 waves per batch, chunk-skewed wavefront ----------
// lane i <- lane i-1 via DPP wave_shr:1; lane 0 <- fill
__device__ __forceinline__ float wshr1(float src, float fill) {
    return __int_as_float(__builtin_amdgcn_update_dpp(
        __float_as_int(fill), __float_as_int(src), 0x138, 0xF, 0xF, false));
}

__global__ __launch_bounds__(256) void sdtw_kernel(const unsigned short* __restrict__ Dg,
                                                   float* __restrict__ res) {
    __shared__ unsigned short sd[8][16 * 256];
    __shared__ float bbuf[3][2][16];
    const int b = blockIdx.x;
    const int tid = threadIdx.x;
    const int w = tid >> 6;
    const int lane = tid & 63;
    const float INF = INFINITY;
    const unsigned short* Db = Dg + (size_t)b * NDPAD * 256;

    auto prefetch = [&](int c) {
        #pragma unroll
        for (int q = 0; q < 8; ++q) {
            __builtin_amdgcn_global_load_lds(
                (const __attribute__((address_space(1))) void*)(Db + (size_t)c * 4096 + q * 512 + lane * 8),
                (__attribute__((address_space(3))) void*)(&sd[c & 7][q * 512]),
                16, 0, 0);
        }
    };

    const int col0 = 64 * w + lane;
    float rm1 = INF, rm2 = INF;
    float p2carry = (tid == 0) ? 0.0f : INF;
    float bcarry = INF;

    if (w == 0) {
        prefetch(0);
        prefetch(1);
        asm volatile("s_waitcnt vmcnt(8)" ::: "memory");
    }
    asm volatile("s_waitcnt lgkmcnt(0)" ::: "memory");
    __builtin_amdgcn_s_barrier();

    for (int r = 0; r < 35; ++r) {
        if (w == 0 && r + 2 < 32) prefetch(r + 2);
        const int c = r - w;
        if (0 <= c && c < 32) {
            const unsigned short* Lp = &sd[c & 7][0];
            float dv[16];
            #pragma unroll
            for (int q = 0; q < 16; ++q)
                dv[q] = bf2f(Lp[q * 256 + col0]);

            float bv[16];
            if (w == 0) {
                #pragma unroll
                for (int q = 0; q < 16; ++q) bv[q] = INF;
            } else {
                const float4* bp4 = (const float4*)&bbuf[w - 1][c & 1][0];
                float4 b0 = bp4[0], b1 = bp4[1], b2 = bp4[2], b3 = bp4[3];
                bv[0] = bcarry;
                bv[1] = b0.x;  bv[2] = b0.y;  bv[3] = b0.z;  bv[4] = b0.w;
                bv[5] = b1.x;  bv[6] = b1.y;  bv[7] = b1.z;  bv[8] = b1.w;
                bv[9] = b2.x;  bv[10] = b2.y; bv[11] = b2.z; bv[12] = b2.w;
                bv[13] = b3.x; bv[14] = b3.y; bv[15] = b3.z;
                bcarry = b3.w;
            }
            asm volatile("s_waitcnt lgkmcnt(0)" ::: "memory");
            __builtin_amdgcn_sched_barrier(0);

            const int ibase = 16 * c - col0;
            float bb[16];
            #pragma unroll
            for (int q = 0; q < 16; ++q) {
                float p1 = wshr1(rm1, bv[q]);
                float p2 = p2carry;
                p2carry = p1;
                float m   = fminf(p2, fminf(rm1, p1));
                float mid = __builtin_amdgcn_fmed3f(p2, rm1, p1);
                float M   = fmaxf(p2, fmaxf(rm1, p1));
                float s   = (__builtin_amdgcn_exp2f(m - mid) +
                             __builtin_amdgcn_exp2f(m - M)) + 1.0f;
                float rcv = dv[q] + m - __builtin_amdgcn_logf(s);
                bool valid = (unsigned)(ibase + q) < 256u;
                rcv = valid ? rcv : INF;
                rm2 = rm1;
                rm1 = rcv;
                bb[q] = rcv;
            }
            if (w < 3 && lane == 63) {
                float4* op = (float4*)&bbuf[w][c & 1][0];
                op[0] = make_float4(bb[0], bb[1], bb[2], bb[3]);
                op[1] = make_float4(bb[4], bb[5], bb[6], bb[7]);
                op[2] = make_float4(bb[8], bb[9], bb[10], bb[11]);
                op[3] = make_float4(bb[12], bb[13], bb[14], bb[15]);
            }
        }
        if (w == 0) {
            if (r < 30) asm volatile("s_waitcnt vmcnt(8)" ::: "memory");
            else        asm volatile("s_waitcnt vmcnt(0)" ::: "memory");
        }
        asm volatile("s_waitcnt lgkmcnt(0)" ::: "memory");
        __builtin_amdgcn_s_barrier();
    }
    if (tid == 255) res[b] = rm2 * LN2;
}

// ---------- final mean over batches ----------
__global__ void reduce_kernel(const float* __restrict__ res, float* __restrict__ out) {
    int t = threadIdx.x;
    float v = res[t];
    #pragma unroll
    for (int off = 32; off; off >>= 1) v += __shfl_down(v, off, 64);
    if (t == 0) out[0] = v * (1.0f / BB);
}

extern "C" void kernel_launch(void* const* d_in, const int* in_sizes, int n_in,
                              void* d_out, int out_size, void* d_ws, size_t ws_size,
                              hipStream_t stream) {
    const float* S = (const float*)d_in[0];
    const float* T = (const float*)d_in[1];

    const size_t nDiag = (size_t)BB * NDPAD * 256;   // 8,388,608 ushorts (16.8 MB)
    unsigned short* diag = (unsigned short*)d_ws;
    float* rsv = (float*)(diag + nDiag);

    fused_kernel<<<dim3(BB, 16), 256, 0, stream>>>(S, T, diag);
    sdtw_kernel<<<BB, 256, 0, stream>>>(diag, rsv);
    reduce_kernel<<<1, 64, 0, stream>>>(rsv, (float*)d_out);
}

// Round 20
// 80.740 us; speedup vs baseline: 1.0057x; 1.0057x over previous
//
#include <hip/hip_runtime.h>
#include <math.h>

#define BB 64
#define LL 256
#define DD 1024
#define NDPAD 512   // padded anti-diagonal count per batch (511 real + 1 pad)
#define LOG2E 1.4426950408889634f
#define LN2   0.6931471805599453f

typedef __attribute__((ext_vector_type(8))) short short8v;
typedef __attribute__((ext_vector_type(4))) float float4v;

__device__ __forceinline__ unsigned short f2bf(float f) {
    unsigned u = __float_as_uint(f);
    unsigned r = (u + 0x7fffu + ((u >> 16) & 1u)) >> 16;   // RNE
    return (unsigned short)r;
}
__device__ __forceinline__ float bf2f(unsigned short u) {
    return __uint_as_float(((unsigned)u) << 16);
}
// packed RNE convert: dst = (bf16(hi)<<16) | bf16(lo)
__device__ __forceinline__ unsigned cvtpk(float lo, float hi) {
    unsigned r;
    asm("v_cvt_pk_bf16_f32 %0, %1, %2" : "=v"(r) : "v"(lo), "v"(hi));
    return r;
}

// ---------- fused: fp32 -> bf16 staging + row norms + MFMA dist GEMM ----------
// 128x128 tile, grid (BB,4), 512 thr. BK=128 macro-chunks, double-buffered LDS
// (2 x 64KB). Staging: per wave 8 instrs/side, each 512B CONTIGUOUS from 2 rows
// (4-line bursts; R8-R18 staged 16 scattered lines/instr), 16 loads in flight,
// 1 barrier per macro-step (9 total vs 32). Full K=1024 per block.
// LDS layout: [row][128 bf16] (256B row stride); 16B slot s of row r at phys
// s^(r&7): staging ds_write_b64 2-way, frag ds_read_b128 2-way (both free).
__global__ __launch_bounds__(512) void fused_kernel(const float* __restrict__ S,
                                                    const float* __restrict__ T,
                                                    unsigned short* __restrict__ Dd) {
    __shared__ unsigned short ldsA[2][128 * 128];   // 64 KB
    __shared__ unsigned short ldsB[2][128 * 128];   // 64 KB
    __shared__ float nrm[2][128];

    const int b    = blockIdx.x;
    const int tile = blockIdx.y;
    const int i0 = (tile & 1) * 128;
    const int j0 = (tile >> 1) * 128;
    const int tid = threadIdx.x, w = tid >> 6, lane = tid & 63;
    const int wr = w >> 2, wc = w & 3;              // wave output tile 64x32

    const float* Sg = S + ((size_t)b * LL + i0) * DD;
    const float* Tg = T + ((size_t)b * LL + j0) * DD;

    // staging decomposition: instr t covers rows wrow+2t, wrow+2t+1 (h = lane>>5),
    // lane reads 16B fp32 unit u (u = lane&31) at XOR-permuted 32B granularity.
    const int h    = lane >> 5;
    const int u    = lane & 31;
    const int wrow = w * 16;

    float4v acc[4][2];
    const float4v fzero = {0.f, 0.f, 0.f, 0.f};
    #pragma unroll
    for (int mi = 0; mi < 4; ++mi)
        #pragma unroll
        for (int ni = 0; ni < 2; ++ni) acc[mi][ni] = fzero;

    float4 lda[8], ldb[8];                  // in-flight chunk (static-indexed only)
    float ns_a[8] = {0.f, 0.f, 0.f, 0.f, 0.f, 0.f, 0.f, 0.f};
    float ns_b[8] = {0.f, 0.f, 0.f, 0.f, 0.f, 0.f, 0.f, 0.f};

    auto issue = [&](int ms) {
        #pragma unroll
        for (int t = 0; t < 8; ++t) {
            int row = wrow + 2 * t + h;
            int p   = (u >> 1) ^ ((2 * t + h) & 7);     // phys 16B slot
            int fo  = ms * 128 + p * 8 + (u & 1) * 4;   // fp32 index within row
            lda[t] = *(const float4*)(Sg + (size_t)row * DD + fo);
            ldb[t] = *(const float4*)(Tg + (size_t)row * DD + fo);
        }
    };

    auto commit = [&](int buf) {
        #pragma unroll
        for (int t = 0; t < 8; ++t) {
            int row = wrow + 2 * t + h;
            int p   = (u >> 1) ^ ((2 * t + h) & 7);
            int ho  = row * 128 + p * 8 + (u & 1) * 4;  // ushort index
            float4 va = lda[t];
            ns_a[t] += va.x * va.x + va.y * va.y + va.z * va.z + va.w * va.w;
            uint2 oa;
            oa.x = cvtpk(va.x, va.y);
            oa.y = cvtpk(va.z, va.w);
            *(uint2*)(&ldsA[buf][ho]) = oa;
            float4 vb = ldb[t];
            ns_b[t] += vb.x * vb.x + vb.y * vb.y + vb.z * vb.z + vb.w * vb.w;
            uint2 ob;
            ob.x = cvtpk(vb.x, vb.y);
            ob.y = cvtpk(vb.z, vb.w);
            *(uint2*)(&ldsB[buf][ho]) = ob;
        }
    };

    auto compute = [&](int buf) {
        #pragma unroll
        for (int kk = 0; kk < 4; ++kk) {               // 4 substeps of K=32
            short8v af[4], bf[2];
            #pragma unroll
            for (int mi = 0; mi < 4; ++mi) {
                int row  = wr * 64 + mi * 16 + (lane & 15);
                int phys = (kk * 4 + (lane >> 4)) ^ (row & 7);
                af[mi] = *(const short8v*)(&ldsA[buf][row * 128 + phys * 8]);
            }
            #pragma unroll
            for (int ni = 0; ni < 2; ++ni) {
                int row  = wc * 32 + ni * 16 + (lane & 15);
                int phys = (kk * 4 + (lane >> 4)) ^ (row & 7);
                bf[ni] = *(const short8v*)(&ldsB[buf][row * 128 + phys * 8]);
            }
            #pragma unroll
            for (int mi = 0; mi < 4; ++mi)
                #pragma unroll
                for (int ni = 0; ni < 2; ++ni)
                    acc[mi][ni] = __builtin_amdgcn_mfma_f32_16x16x32_bf16(af[mi], bf[ni],
                                                                          acc[mi][ni], 0, 0, 0);
        }
    };

    issue(0);
    commit(0);
    __syncthreads();
    for (int ms = 0; ms < 8; ++ms) {
        if (ms + 1 < 8) issue(ms + 1);      // 16 loads fly under compute
        compute(ms & 1);
        if (ms + 1 < 8) commit((ms + 1) & 1);
        __syncthreads();
    }

    // row norms: reduce the 32 lane-partials of each row (within 32-lane half)
    #pragma unroll
    for (int t = 0; t < 8; ++t) {
        float s = ns_a[t];
        s += __shfl_xor(s, 1, 64);
        s += __shfl_xor(s, 2, 64);
        s += __shfl_xor(s, 4, 64);
        s += __shfl_xor(s, 8, 64);
        s += __shfl_xor(s, 16, 64);
        if (u == 0) nrm[0][wrow + 2 * t + h] = s;
        float sb = ns_b[t];
        sb += __shfl_xor(sb, 1, 64);
        sb += __shfl_xor(sb, 2, 64);
        sb += __shfl_xor(sb, 4, 64);
        sb += __shfl_xor(sb, 8, 64);
        sb += __shfl_xor(sb, 16, 64);
        if (u == 0) nrm[1][wrow + 2 * t + h] = sb;
    }
    __syncthreads();

    // epilogue: sq = ||s||^2 + ||t||^2 - 2*dot -> sqrt -> bf16 * LOG2E, diag-major
    const int r0 = (lane >> 4) * 4;
    const int cf = lane & 15;
    unsigned short* Db = Dd + (size_t)b * NDPAD * 256;
    #pragma unroll
    for (int mi = 0; mi < 4; ++mi) {
        #pragma unroll
        for (int ni = 0; ni < 2; ++ni) {
            int lj = wc * 32 + ni * 16 + cf;
            float tj = nrm[1][lj];
            int j = j0 + lj;
            #pragma unroll
            for (int rg = 0; rg < 4; ++rg) {
                int li = wr * 64 + mi * 16 + r0 + rg;
                float sq = nrm[0][li] + tj - 2.0f * acc[mi][ni][rg];
                float dv = sqrtf(fmaxf(sq, 1e-12f));
                int i = i0 + li;
                Db[(size_t)(i + j) * 256 + j] = f2bf(dv * LOG2E);
            }
        }
    }
}

// ---------- soft-DTW DP: 4 waves per batch, chunk-skewed wavefront ----------
// lane i <- lane i-1 via DPP wave_shr:1; lane 0 <- fill
__device__ __forceinline__ float wshr1(float src, float fill) {
    return __int_as_float(__builtin_amdgcn_update_dpp(
        __float_as_int(fill), __float_as_int(src), 0x138, 0xF, 0xF, false));
}

__global__ __launch_bounds__(256) void sdtw_kernel(const unsigned short* __restrict__ Dg,
                                                   float* __restrict__ res) {
    __shared__ unsigned short sd[8][16 * 256];
    __shared__ float bbuf[3][2][16];
    const int b = blockIdx.x;
    const int tid = threadIdx.x;
    const int w = tid >> 6;
    const int lane = tid & 63;
    const float INF = INFINITY;
    const unsigned short* Db = Dg + (size_t)b * NDPAD * 256;

    auto prefetch = [&](int c) {
        #pragma unroll
        for (int q = 0; q < 8; ++q) {
            __builtin_amdgcn_global_load_lds(
                (const __attribute__((address_space(1))) void*)(Db + (size_t)c * 4096 + q * 512 + lane * 8),
                (__attribute__((address_space(3))) void*)(&sd[c & 7][q * 512]),
                16, 0, 0);
        }
    };

    const int col0 = 64 * w + lane;
    float rm1 = INF, rm2 = INF;
    float p2carry = (tid == 0) ? 0.0f : INF;
    float bcarry = INF;

    if (w == 0) {
        prefetch(0);
        prefetch(1);
        asm volatile("s_waitcnt vmcnt(8)" ::: "memory");
    }
    asm volatile("s_waitcnt lgkmcnt(0)" ::: "memory");
    __builtin_amdgcn_s_barrier();

    for (int r = 0; r < 35; ++r) {
        if (w == 0 && r + 2 < 32) prefetch(r + 2);
        const int c = r - w;
        if (0 <= c && c < 32) {
            const unsigned short* Lp = &sd[c & 7][0];
            float dv[16];
            #pragma unroll
            for (int q = 0; q < 16; ++q)
                dv[q] = bf2f(Lp[q * 256 + col0]);

            float bv[16];
            if (w == 0) {
                #pragma unroll
                for (int q = 0; q < 16; ++q) bv[q] = INF;
            } else {
                const float4* bp4 = (const float4*)&bbuf[w - 1][c & 1][0];
                float4 b0 = bp4[0], b1 = bp4[1], b2 = bp4[2], b3 = bp4[3];
                bv[0] = bcarry;
                bv[1] = b0.x;  bv[2] = b0.y;  bv[3] = b0.z;  bv[4] = b0.w;
                bv[5] = b1.x;  bv[6] = b1.y;  bv[7] = b1.z;  bv[8] = b1.w;
                bv[9] = b2.x;  bv[10] = b2.y; bv[11] = b2.z; bv[12] = b2.w;
                bv[13] = b3.x; bv[14] = b3.y; bv[15] = b3.z;
                bcarry = b3.w;
            }
            asm volatile("s_waitcnt lgkmcnt(0)" ::: "memory");
            __builtin_amdgcn_sched_barrier(0);

            const int ibase = 16 * c - col0;
            float bb[16];
            #pragma unroll
            for (int q = 0; q < 16; ++q) {
                float p1 = wshr1(rm1, bv[q]);
                float p2 = p2carry;
                p2carry = p1;
                float m   = fminf(p2, fminf(rm1, p1));
                float mid = __builtin_amdgcn_fmed3f(p2, rm1, p1);
                float M   = fmaxf(p2, fmaxf(rm1, p1));
                float s   = (__builtin_amdgcn_exp2f(m - mid) +
                             __builtin_amdgcn_exp2f(m - M)) + 1.0f;
                float rcv = dv[q] + m - __builtin_amdgcn_logf(s);
                bool valid = (unsigned)(ibase + q) < 256u;
                rcv = valid ? rcv : INF;
                rm2 = rm1;
                rm1 = rcv;
                bb[q] = rcv;
            }
            if (w < 3 && lane == 63) {
                float4* op = (float4*)&bbuf[w][c & 1][0];
                op[0] = make_float4(bb[0], bb[1], bb[2], bb[3]);
                op[1] = make_float4(bb[4], bb[5], bb[6], bb[7]);
                op[2] = make_float4(bb[8], bb[9], bb[10], bb[11]);
                op[3] = make_float4(bb[12], bb[13], bb[14], bb[15]);
            }
        }
        if (w == 0) {
            if (r < 30) asm volatile("s_waitcnt vmcnt(8)" ::: "memory");
            else        asm volatile("s_waitcnt vmcnt(0)" ::: "memory");
        }
        asm volatile("s_waitcnt lgkmcnt(0)" ::: "memory");
        __builtin_amdgcn_s_barrier();
    }
    if (tid == 255) res[b] = rm2 * LN2;
}

// ---------- final mean over batches ----------
__global__ void reduce_kernel(const float* __restrict__ res, float* __restrict__ out) {
    int t = threadIdx.x;
    float v = res[t];
    #pragma unroll
    for (int off = 32; off; off >>= 1) v += __shfl_down(v, off, 64);
    if (t == 0) out[0] = v * (1.0f / BB);
}

extern "C" void kernel_launch(void* const* d_in, const int* in_sizes, int n_in,
                              void* d_out, int out_size, void* d_ws, size_t ws_size,
                              hipStream_t stream) {
    const float* S = (const float*)d_in[0];
    const float* T = (const float*)d_in[1];

    const size_t nDiag = (size_t)BB * NDPAD * 256;   // 8,388,608 ushorts (16.8 MB)
    unsigned short* diag = (unsigned short*)d_ws;
    float* rsv = (float*)(diag + nDiag);

    fused_kernel<<<dim3(BB, 4), 512, 0, stream>>>(S, T, diag);
    sdtw_kernel<<<BB, 256, 0, stream>>>(diag, rsv);
    reduce_kernel<<<1, 64, 0, stream>>>(rsv, (float*)d_out);
}

// Round 21
// 75.712 us; speedup vs baseline: 1.0725x; 1.0664x over previous
//
#include <hip/hip_runtime.h>
#include <math.h>

#define BB 64
#define LL 256
#define DD 1024
#define NDPAD 512   // padded anti-diagonal count per batch (511 real + 1 pad)
#define BK 32
#define LOG2E 1.4426950408889634f
#define LN2   0.6931471805599453f

typedef __attribute__((ext_vector_type(8))) short short8v;
typedef __attribute__((ext_vector_type(4))) float float4v;

__device__ __forceinline__ unsigned short f2bf(float f) {
    unsigned u = __float_as_uint(f);
    unsigned r = (u + 0x7fffu + ((u >> 16) & 1u)) >> 16;   // RNE
    return (unsigned short)r;
}
__device__ __forceinline__ float bf2f(unsigned short u) {
    return __uint_as_float(((unsigned)u) << 16);
}
// packed RNE convert: dst = (bf16(hi)<<16) | bf16(lo)
__device__ __forceinline__ unsigned cvtpk(float lo, float hi) {
    unsigned r;
    asm("v_cvt_pk_bf16_f32 %0, %1, %2" : "=v"(r) : "v"(lo), "v"(hi));
    return r;
}

// ---------- fused: fp32 load -> bf16 LDS staging + row norms + MFMA dist GEMM ----------
// R16 structure (best: 58us): 128x128 tile, grid (BB,4), 512 thr, in-block K-split
// (waves 0-3 k<512, waves 4-7 k>=512), conflict-free swizzle s^((r>>1)&3),
// lgkm-only phase barriers. THIS ROUND: epilogue rewritten — dv tile staged to
// LDS, then stored along ANTI-DIAGONALS (contiguous in diag-major layout) as
// aligned 16B dwordx4 (4096 stores/block vs 16384 scalar scattered).
__global__ __launch_bounds__(512) void fused_kernel(const float* __restrict__ S,
                                                    const float* __restrict__ T,
                                                    unsigned short* __restrict__ Dd) {
    __shared__ unsigned short lds[2][2][2][128 * BK];   // [pipe][buf][A/B], 64 KB
    __shared__ float nrmP[2][2][128];                   // partial norms [pipe][side][row]

    const int b    = blockIdx.x;
    const int tile = blockIdx.y;
    const int i0 = (tile & 1) * 128;
    const int j0 = (tile >> 1) * 128;
    const int tid = threadIdx.x, w = tid >> 6, lane = tid & 63;
    const int p = w >> 2;                    // K-pipeline (0: k<512, 1: k>=512)
    const int q = w & 3;                     // role within pipeline
    const int wr = q >> 1, wc = q & 1;
    const int kbase = p * 512;

    const float* Sg = S + ((size_t)b * LL + i0) * DD;
    const float* Tg = T + ((size_t)b * LL + j0) * DD;

    const int sr   = q * 16 + (lane >> 2);   // staging row within 64-row half
    const int slot = lane & 3;               // lds PHYS k-slot this lane fills
    const int kb   = slot ^ ((sr >> 1) & 3); // GLOBAL k-slot (conflict-free swizzle)

    float4v acc[4][4];
    const float4v fzero = {0.f, 0.f, 0.f, 0.f};
    #pragma unroll
    for (int mi = 0; mi < 4; ++mi)
        #pragma unroll
        for (int ni = 0; ni < 4; ++ni) acc[mi][ni] = fzero;

    struct Stg { float4 a[2][2]; float4 bb[2][2]; };   // [half n][8-float piece]
    Stg st0, st1;
    float ns[2][2] = {};                      // norm accum [side][n]

    auto issue = [&](Stg& s, int kt) {
        const float* pa = Sg + (size_t)sr * DD + kbase + kt * BK + kb * 8;
        const float* pb = Tg + (size_t)sr * DD + kbase + kt * BK + kb * 8;
        s.a[0][0]  = *(const float4*)(pa);
        s.a[0][1]  = *(const float4*)(pa + 4);
        s.a[1][0]  = *(const float4*)(pa + 64 * DD);
        s.a[1][1]  = *(const float4*)(pa + 64 * DD + 4);
        s.bb[0][0] = *(const float4*)(pb);
        s.bb[0][1] = *(const float4*)(pb + 4);
        s.bb[1][0] = *(const float4*)(pb + 64 * DD);
        s.bb[1][1] = *(const float4*)(pb + 64 * DD + 4);
    };

    auto cvtwrite = [&](const float4& v0, const float4& v1, unsigned short* dst, float& nacc) {
        nacc += v0.x * v0.x + v0.y * v0.y + v0.z * v0.z + v0.w * v0.w
              + v1.x * v1.x + v1.y * v1.y + v1.z * v1.z + v1.w * v1.w;
        uint4 o;
        o.x = cvtpk(v0.x, v0.y);
        o.y = cvtpk(v0.z, v0.w);
        o.z = cvtpk(v1.x, v1.y);
        o.w = cvtpk(v1.z, v1.w);
        *(uint4*)dst = o;
    };

    auto commit = [&](Stg& s, int buf) {
        #pragma unroll
        for (int n = 0; n < 2; ++n) {
            cvtwrite(s.a[n][0],  s.a[n][1],  &lds[p][buf][0][(n * 64 + sr) * BK + slot * 8], ns[0][n]);
            cvtwrite(s.bb[n][0], s.bb[n][1], &lds[p][buf][1][(n * 64 + sr) * BK + slot * 8], ns[1][n]);
        }
    };

    auto compute = [&](int buf) {
        const unsigned short* LA = &lds[p][buf][0][0];
        const unsigned short* LB = &lds[p][buf][1][0];
        short8v af[4], bf[4];
        #pragma unroll
        for (int mi = 0; mi < 4; ++mi) {
            int row = wr * 64 + mi * 16 + (lane & 15);
            int kbf = (lane >> 4) ^ ((row >> 1) & 3);   // conflict-free read swizzle
            af[mi] = *(const short8v*)(LA + row * BK + kbf * 8);
        }
        #pragma unroll
        for (int ni = 0; ni < 4; ++ni) {
            int row = wc * 64 + ni * 16 + (lane & 15);
            int kbf = (lane >> 4) ^ ((row >> 1) & 3);
            bf[ni] = *(const short8v*)(LB + row * BK + kbf * 8);
        }
        #pragma unroll
        for (int mi = 0; mi < 4; ++mi)
            #pragma unroll
            for (int ni = 0; ni < 4; ++ni)
                acc[mi][ni] = __builtin_amdgcn_mfma_f32_16x16x32_bf16(af[mi], bf[ni],
                                                                      acc[mi][ni], 0, 0, 0);
    };

    // k-loop barrier: drain ONLY lgkm (own LDS ops); leave global loads in flight.
    auto phase_barrier = [&]() {
        asm volatile("s_waitcnt lgkmcnt(0)" ::: "memory");
        __builtin_amdgcn_s_barrier();
        __builtin_amdgcn_sched_barrier(0);
    };

    issue(st0, 0);
    for (int kt2 = 0; kt2 < 16; kt2 += 2) {
        issue(st1, kt2 + 1);
        commit(st0, 0);
        phase_barrier();
        compute(0);
        if (kt2 + 2 < 16) issue(st0, kt2 + 2);
        commit(st1, 1);
        phase_barrier();
        compute(1);
    }

    // partial row norms: reduce across the 4 slot-lanes of each row group
    #pragma unroll
    for (int side = 0; side < 2; ++side)
        #pragma unroll
        for (int n = 0; n < 2; ++n) {
            float s = ns[side][n];
            s += __shfl_xor(s, 1, 64);
            s += __shfl_xor(s, 2, 64);
            if (slot == 0) nrmP[p][side][n * 64 + sr] = s;
        }
    __syncthreads();                         // staging reads done; norms visible

    // combine pipeline-1 partial accs into pipeline-0 (reuse staging LDS, 64 KB)
    float* cb = (float*)&lds[0][0][0][0];
    if (p == 1) {
        #pragma unroll
        for (int mi = 0; mi < 4; ++mi)
            #pragma unroll
            for (int ni = 0; ni < 4; ++ni)
                *(float4v*)(cb + q * 4096 + (mi * 4 + ni) * 256 + lane * 4) = acc[mi][ni];
    }
    __syncthreads();

    if (p == 0) {
        #pragma unroll
        for (int mi = 0; mi < 4; ++mi)
            #pragma unroll
            for (int ni = 0; ni < 4; ++ni)
                acc[mi][ni] += *(const float4v*)(cb + q * 4096 + (mi * 4 + ni) * 256 + lane * 4);
    }
    __syncthreads();                         // all cb reads done; LDS reusable

    // stage dv tile (bf16, [li][lj], stride 136) into LDS (reuses staging buffer)
    unsigned short* ldsT = &lds[0][0][0][0]; // 128*136*2 = 34816 B <= 64 KB
    if (p == 0) {
        const int r0 = (lane >> 4) * 4;
        const int cf = lane & 15;
        #pragma unroll
        for (int mi = 0; mi < 4; ++mi) {
            #pragma unroll
            for (int ni = 0; ni < 4; ++ni) {
                int lj = wc * 64 + ni * 16 + cf;
                float tj = nrmP[0][1][lj] + nrmP[1][1][lj];
                #pragma unroll
                for (int rg = 0; rg < 4; ++rg) {
                    int li = wr * 64 + mi * 16 + r0 + rg;
                    float sq = nrmP[0][0][li] + nrmP[1][0][li] + tj - 2.0f * acc[mi][ni][rg];
                    float dv = sqrtf(fmaxf(sq, 1e-12f));
                    ldsT[li * 136 + lj] = f2bf(dv * LOG2E);
                }
            }
        }
    }
    __syncthreads();

    // store along anti-diagonals: contiguous in diag-major layout -> 16B stores.
    // thread pair (tid>>1) owns local diagonal cl; (tid&1) picks lj half.
    {
        const int cl = tid >> 1;                     // 0..255 (255 unused)
        if (cl < 255) {
            const int d = cl + i0 + j0;
            unsigned short* Dp = Dd + (size_t)b * NDPAD * 256 + (size_t)d * 256 + j0;
            const int ljmin = cl > 127 ? cl - 127 : 0;
            const int ljmax = cl < 127 ? cl : 127;
            const int lb = (tid & 1) * 64;           // this thread's lj base
            #pragma unroll
            for (int kc = 0; kc < 8; ++kc) {
                int l0 = lb + kc * 8;
                if (l0 > ljmax || l0 + 7 < ljmin) continue;
                unsigned e[8];
                #pragma unroll
                for (int x = 0; x < 8; ++x) {
                    int lj = l0 + x;
                    int li = cl - lj;
                    int lic = li < 0 ? 0 : (li > 127 ? 127 : li);
                    e[x] = ldsT[lic * 136 + lj];
                }
                if (l0 >= ljmin && l0 + 7 <= ljmax) {
                    uint4 o;
                    o.x = e[0] | (e[1] << 16);
                    o.y = e[2] | (e[3] << 16);
                    o.z = e[4] | (e[5] << 16);
                    o.w = e[6] | (e[7] << 16);
                    *(uint4*)(Dp + l0) = o;          // 16B aligned: j0,l0 ≡ 0 mod 8
                } else {
                    #pragma unroll
                    for (int x = 0; x < 8; ++x) {
                        int lj = l0 + x;
                        if (lj >= ljmin && lj <= ljmax)
                            Dp[lj] = (unsigned short)e[x];
                    }
                }
            }
        }
    }
}

// ---------- soft-DTW DP: 4 waves per batch, chunk-skewed wavefront ----------
// lane i <- lane i-1 via DPP wave_shr:1; lane 0 <- fill
__device__ __forceinline__ float wshr1(float src, float fill) {
    return __int_as_float(__builtin_amdgcn_update_dpp(
        __float_as_int(fill), __float_as_int(src), 0x138, 0xF, 0xF, false));
}

__global__ __launch_bounds__(256) void sdtw_kernel(const unsigned short* __restrict__ Dg,
                                                   float* __restrict__ res) {
    __shared__ unsigned short sd[8][16 * 256];
    __shared__ float bbuf[3][2][16];
    const int b = blockIdx.x;
    const int tid = threadIdx.x;
    const int w = tid >> 6;
    const int lane = tid & 63;
    const float INF = INFINITY;
    const unsigned short* Db = Dg + (size_t)b * NDPAD * 256;

    auto prefetch = [&](int c) {
        #pragma unroll
        for (int q = 0; q < 8; ++q) {
            __builtin_amdgcn_global_load_lds(
                (const __attribute__((address_space(1))) void*)(Db + (size_t)c * 4096 + q * 512 + lane * 8),
                (__attribute__((address_space(3))) void*)(&sd[c & 7][q * 512]),
                16, 0, 0);
        }
    };

    const int col0 = 64 * w + lane;
    float rm1 = INF, rm2 = INF;
    float p2carry = (tid == 0) ? 0.0f : INF;
    float bcarry = INF;

    if (w == 0) {
        prefetch(0);
        prefetch(1);
        asm volatile("s_waitcnt vmcnt(8)" ::: "memory");
    }
    asm volatile("s_waitcnt lgkmcnt(0)" ::: "memory");
    __builtin_amdgcn_s_barrier();

    for (int r = 0; r < 35; ++r) {
        if (w == 0 && r + 2 < 32) prefetch(r + 2);
        const int c = r - w;
        if (0 <= c && c < 32) {
            const unsigned short* Lp = &sd[c & 7][0];
            float dv[16];
            #pragma unroll
            for (int q = 0; q < 16; ++q)
                dv[q] = bf2f(Lp[q * 256 + col0]);

            float bv[16];
            if (w == 0) {
                #pragma unroll
                for (int q = 0; q < 16; ++q) bv[q] = INF;
            } else {
                const float4* bp4 = (const float4*)&bbuf[w - 1][c & 1][0];
                float4 b0 = bp4[0], b1 = bp4[1], b2 = bp4[2], b3 = bp4[3];
                bv[0] = bcarry;
                bv[1] = b0.x;  bv[2] = b0.y;  bv[3] = b0.z;  bv[4] = b0.w;
                bv[5] = b1.x;  bv[6] = b1.y;  bv[7] = b1.z;  bv[8] = b1.w;
                bv[9] = b2.x;  bv[10] = b2.y; bv[11] = b2.z; bv[12] = b2.w;
                bv[13] = b3.x; bv[14] = b3.y; bv[15] = b3.z;
                bcarry = b3.w;
            }
            asm volatile("s_waitcnt lgkmcnt(0)" ::: "memory");
            __builtin_amdgcn_sched_barrier(0);

            const int ibase = 16 * c - col0;
            float bb[16];
            #pragma unroll
            for (int q = 0; q < 16; ++q) {
                float p1 = wshr1(rm1, bv[q]);
                float p2 = p2carry;
                p2carry = p1;
                float m   = fminf(p2, fminf(rm1, p1));
                float mid = __builtin_amdgcn_fmed3f(p2, rm1, p1);
                float M   = fmaxf(p2, fmaxf(rm1, p1));
                float s   = (__builtin_amdgcn_exp2f(m - mid) +
                             __builtin_amdgcn_exp2f(m - M)) + 1.0f;
                float rcv = dv[q] + m - __builtin_amdgcn_logf(s);
                bool valid = (unsigned)(ibase + q) < 256u;
                rcv = valid ? rcv : INF;
                rm2 = rm1;
                rm1 = rcv;
                bb[q] = rcv;
            }
            if (w < 3 && lane == 63) {
                float4* op = (float4*)&bbuf[w][c & 1][0];
                op[0] = make_float4(bb[0], bb[1], bb[2], bb[3]);
                op[1] = make_float4(bb[4], bb[5], bb[6], bb[7]);
                op[2] = make_float4(bb[8], bb[9], bb[10], bb[11]);
                op[3] = make_float4(bb[12], bb[13], bb[14], bb[15]);
            }
        }
        if (w == 0) {
            if (r < 30) asm volatile("s_waitcnt vmcnt(8)" ::: "memory");
            else        asm volatile("s_waitcnt vmcnt(0)" ::: "memory");
        }
        asm volatile("s_waitcnt lgkmcnt(0)" ::: "memory");
        __builtin_amdgcn_s_barrier();
    }
    if (tid == 255) res[b] = rm2 * LN2;
}

// ---------- final mean over batches ----------
__global__ void reduce_kernel(const float* __restrict__ res, float* __restrict__ out) {
    int t = threadIdx.x;
    float v = res[t];
    #pragma unroll
    for (int off = 32; off; off >>= 1) v += __shfl_down(v, off, 64);
    if (t == 0) out[0] = v * (1.0f / BB);
}

extern "C" void kernel_launch(void* const* d_in, const int* in_sizes, int n_in,
                              void* d_out, int out_size, void* d_ws, size_t ws_size,
                              hipStream_t stream) {
    const float* S = (const float*)d_in[0];
    const float* T = (const float*)d_in[1];

    const size_t nDiag = (size_t)BB * NDPAD * 256;   // 8,388,608 ushorts (16.8 MB)
    unsigned short* diag = (unsigned short*)d_ws;
    float* rsv = (float*)(diag + nDiag);

    fused_kernel<<<dim3(BB, 4), 512, 0, stream>>>(S, T, diag);
    sdtw_kernel<<<BB, 256, 0, stream>>>(diag, rsv);
    reduce_kernel<<<1, 64, 0, stream>>>(rsv, (float*)d_out);
}